// Round 6
// baseline (27.440 us; speedup 1.0000x reference)
//
#include <hip/hip_runtime.h>
#include <math.h>

#define N_NODES 2048
#define N_RELS  16
#define N_FEAT  256
#define N_JOBS  17               // 16 relation dots + 1 outer_weight dot
#define THREADS 256
#define BLOCKS  512              // 2048 waves == N_NODES; 2 blocks/CU (safe)

typedef int   v2i __attribute__((ext_vector_type(2)));
typedef float v2f __attribute__((ext_vector_type(2)));

__device__ __forceinline__ float sigmoidf_fast(float z) {
    return 1.0f / (1.0f + __expf(-z));
}

// Single PLAIN launch (no cooperative dispatch — R2/R3 showed coop launch
// costs ~50us under graph capture). Co-residency for the spin barrier is
// guaranteed by capacity: 512 blocks of 256 thr, VGPR capped <=128 via
// __launch_bounds__(256,4) -> >=4 blocks/CU capacity on 256 CUs (2x margin).
__global__ void __launch_bounds__(THREADS, 4)
fused_kernel(const float* __restrict__ x,
             const float* __restrict__ relations,
             const float* __restrict__ outer_weight,
             const int* __restrict__ edge_index,
             float* __restrict__ out,
             float* A,            // [N_RELS][N_NODES] in d_ws
             float* B,            // [N_NODES] in d_ws
             unsigned int* ctr,   // barrier counter (memset to 0 each call)
             int E)
{
    const int t    = blockIdx.x * blockDim.x + threadIdx.x;
    const int w    = t >> 6;   // wave id 0..2047 == node id
    const int lane = t & 63;

    // ---- Phase 1: one wave per node; x row loaded once; 17 independent
    //      dot chains fully unrolled (loads pipelined, reduces interleaved).
    {
        const int n = w;                    // BLOCKS*THREADS/64 == N_NODES
        const float4 xv = reinterpret_cast<const float4*>(x + n * N_FEAT)[lane];
        float acc[N_JOBS];
        #pragma unroll
        for (int j = 0; j < N_JOBS; ++j) {
            const float* rb = (j < N_RELS) ? (relations + j * N_FEAT)
                                           : outer_weight;
            const float4 rv = reinterpret_cast<const float4*>(rb)[lane];
            acc[j] = xv.x * rv.x + xv.y * rv.y + xv.z * rv.z + xv.w * rv.w;
        }
        #pragma unroll
        for (int off = 32; off > 0; off >>= 1) {
            #pragma unroll
            for (int j = 0; j < N_JOBS; ++j)
                acc[j] += __shfl_xor(acc[j], off, 64);
        }
        if (lane == 0) {
            #pragma unroll
            for (int j = 0; j < N_RELS; ++j)
                __hip_atomic_store(&A[j * N_NODES + n], acc[j],
                                   __ATOMIC_RELAXED, __HIP_MEMORY_SCOPE_AGENT);
            __hip_atomic_store(&B[n], acc[N_RELS],
                               __ATOMIC_RELAXED, __HIP_MEMORY_SCOPE_AGENT);
        }
    }

    // ---- Lightweight device-wide barrier (no L2 flush; R3-validated) ----
    asm volatile("s_waitcnt vmcnt(0)" ::: "memory");  // my stores reached MALL
    __syncthreads();
    if (threadIdx.x == 0) {
        __hip_atomic_fetch_add(ctr, 1u, __ATOMIC_RELAXED,
                               __HIP_MEMORY_SCOPE_AGENT);
        while (__hip_atomic_load(ctr, __ATOMIC_RELAXED,
                                 __HIP_MEMORY_SCOPE_AGENT) < BLOCKS) {}
    }
    __syncthreads();

    // ---- Phase 2: 2 edges/thread; agent-scope gathers (stale-L2 safety) ----
    const int* __restrict__ src = edge_index;
    const int* __restrict__ rel = edge_index + E;
    const int* __restrict__ dst = edge_index + 2 * E;

    const int e2 = t * 2;
    if (e2 + 1 < E) {
        const v2i s = *reinterpret_cast<const v2i*>(src + e2);
        const v2i r = *reinterpret_cast<const v2i*>(rel + e2);
        const v2i d = *reinterpret_cast<const v2i*>(dst + e2);
        const float a0 = __hip_atomic_load(&A[r.x * N_NODES + s.x],
                                           __ATOMIC_RELAXED, __HIP_MEMORY_SCOPE_AGENT);
        const float b0 = __hip_atomic_load(&B[d.x],
                                           __ATOMIC_RELAXED, __HIP_MEMORY_SCOPE_AGENT);
        const float a1 = __hip_atomic_load(&A[r.y * N_NODES + s.y],
                                           __ATOMIC_RELAXED, __HIP_MEMORY_SCOPE_AGENT);
        const float b1 = __hip_atomic_load(&B[d.y],
                                           __ATOMIC_RELAXED, __HIP_MEMORY_SCOPE_AGENT);
        v2f o;
        o.x = sigmoidf_fast(a0 * b0);
        o.y = sigmoidf_fast(a1 * b1);
        __builtin_nontemporal_store(o, reinterpret_cast<v2f*>(out + e2));
    } else if (e2 < E) {
        for (int e = e2; e < E; ++e) {
            const float a0 = __hip_atomic_load(&A[rel[e] * N_NODES + src[e]],
                                               __ATOMIC_RELAXED, __HIP_MEMORY_SCOPE_AGENT);
            const float b0 = __hip_atomic_load(&B[dst[e]],
                                               __ATOMIC_RELAXED, __HIP_MEMORY_SCOPE_AGENT);
            out[e] = sigmoidf_fast(a0 * b0);
        }
    }
    // Tail beyond grid capacity (no-op for E = 262144; robustness)
    for (int e = BLOCKS * THREADS * 2 + t; e < E; e += BLOCKS * THREADS) {
        const float a0 = __hip_atomic_load(&A[rel[e] * N_NODES + src[e]],
                                           __ATOMIC_RELAXED, __HIP_MEMORY_SCOPE_AGENT);
        const float b0 = __hip_atomic_load(&B[dst[e]],
                                           __ATOMIC_RELAXED, __HIP_MEMORY_SCOPE_AGENT);
        out[e] = sigmoidf_fast(a0 * b0);
    }
}

extern "C" void kernel_launch(void* const* d_in, const int* in_sizes, int n_in,
                              void* d_out, int out_size, void* d_ws, size_t ws_size,
                              hipStream_t stream) {
    const float* x            = (const float*)d_in[0];
    const float* relations    = (const float*)d_in[1];
    const float* outer_weight = (const float*)d_in[2];
    const int*   edge_index   = (const int*)d_in[3];

    int E = in_sizes[3] / 3;  // edge_index is [3, E]: rows src, rel, dst

    float* A = (float*)d_ws;                         // 128 KB
    float* B = A + N_RELS * N_NODES;                 // 8 KB
    unsigned int* ctr =
        (unsigned int*)((char*)d_ws + 192 * 1024);   // aligned, past A+B
    float* out = (float*)d_out;

    hipMemsetAsync(ctr, 0, sizeof(unsigned int), stream);
    fused_kernel<<<BLOCKS, THREADS, 0, stream>>>(
        x, relations, outer_weight, edge_index, out, A, B, ctr, E);
}

// Round 7
// 12.638 us; speedup vs baseline: 2.1713x; 2.1713x over previous
//
#include <hip/hip_runtime.h>
#include <math.h>

#define N_NODES 2048
#define N_RELS  16
#define N_FEAT  256
#define N_JOBS  17               // 16 relation dots + 1 outer_weight dot
#define THREADS 256

typedef int   v2i __attribute__((ext_vector_type(2)));
typedef float v2f __attribute__((ext_vector_type(2)));

__device__ __forceinline__ float sigmoidf_fast(float z) {
    return 1.0f / (1.0f + __expf(-z));
}

// Kernel 1: one 64-lane wave per node (512 blocks total, 17x fewer than R5's
// 8704). Loads x row once, runs 17 independent dot chains fully unrolled
// (loads pipelined by the compiler), then 17 interleaved shuffle reduces.
__global__ void __launch_bounds__(THREADS)
precompute_kernel(const float* __restrict__ x,
                  const float* __restrict__ relations,
                  const float* __restrict__ outer_weight,
                  float* __restrict__ A,   // [N_RELS][N_NODES]
                  float* __restrict__ B)   // [N_NODES]
{
    const int t    = blockIdx.x * blockDim.x + threadIdx.x;
    const int n    = t >> 6;   // wave id == node id; grid sized exactly
    const int lane = t & 63;

    const float4 xv = reinterpret_cast<const float4*>(x + n * N_FEAT)[lane];

    float acc[N_JOBS];
    #pragma unroll
    for (int j = 0; j < N_JOBS; ++j) {
        const float* rb = (j < N_RELS) ? (relations + j * N_FEAT)
                                       : outer_weight;
        const float4 rv = reinterpret_cast<const float4*>(rb)[lane];
        acc[j] = xv.x * rv.x + xv.y * rv.y + xv.z * rv.z + xv.w * rv.w;
    }
    #pragma unroll
    for (int off = 32; off > 0; off >>= 1) {
        #pragma unroll
        for (int j = 0; j < N_JOBS; ++j)
            acc[j] += __shfl_xor(acc[j], off, 64);
    }
    if (lane == 0) {
        #pragma unroll
        for (int j = 0; j < N_RELS; ++j)
            A[j * N_NODES + n] = acc[j];
        B[n] = acc[N_RELS];
    }
}

// Kernel 2: out[e] = sigmoid(A[rel[e]][src[e]] * B[dst[e]]), 2 edges/thread.
// Plain loads for A/B (L1-cached); nontemporal store for streamed output.
__global__ void __launch_bounds__(THREADS)
edge_kernel(const int* __restrict__ src,
            const int* __restrict__ rel,
            const int* __restrict__ dst,
            const float* __restrict__ A,
            const float* __restrict__ B,
            float* __restrict__ out,
            int E)
{
    const int t  = blockIdx.x * blockDim.x + threadIdx.x;
    const int e2 = t * 2;
    if (e2 + 1 < E) {
        const v2i s = __builtin_nontemporal_load(
            reinterpret_cast<const v2i*>(src + e2));
        const v2i r = __builtin_nontemporal_load(
            reinterpret_cast<const v2i*>(rel + e2));
        const v2i d = __builtin_nontemporal_load(
            reinterpret_cast<const v2i*>(dst + e2));
        // 4 independent gathers, all in flight together
        const float a0 = A[r.x * N_NODES + s.x];
        const float a1 = A[r.y * N_NODES + s.y];
        const float b0 = B[d.x];
        const float b1 = B[d.y];
        v2f o;
        o.x = sigmoidf_fast(a0 * b0);
        o.y = sigmoidf_fast(a1 * b1);
        __builtin_nontemporal_store(o, reinterpret_cast<v2f*>(out + e2));
    } else if (e2 < E) {
        for (int e = e2; e < E; ++e)
            out[e] = sigmoidf_fast(A[rel[e] * N_NODES + src[e]] * B[dst[e]]);
    }
}

extern "C" void kernel_launch(void* const* d_in, const int* in_sizes, int n_in,
                              void* d_out, int out_size, void* d_ws, size_t ws_size,
                              hipStream_t stream) {
    const float* x            = (const float*)d_in[0];
    const float* relations    = (const float*)d_in[1];
    const float* outer_weight = (const float*)d_in[2];
    const int*   edge_index   = (const int*)d_in[3];

    const int E = in_sizes[3] / 3;  // edge_index is [3, E]: rows src, rel, dst
    const int* src = edge_index;
    const int* rel = edge_index + E;
    const int* dst = edge_index + 2 * E;

    float* A = (float*)d_ws;             // 16*2048 floats = 128 KB
    float* B = A + N_RELS * N_NODES;     // 2048 floats = 8 KB

    const int pre_blocks = (N_NODES * 64) / THREADS;   // 512 blocks
    precompute_kernel<<<pre_blocks, THREADS, 0, stream>>>(
        x, relations, outer_weight, A, B);

    const int work = (E + 1) / 2;
    const int edge_blocks = (work + THREADS - 1) / THREADS;  // 512 blocks
    edge_kernel<<<edge_blocks, THREADS, 0, stream>>>(
        src, rel, dst, A, B, (float*)d_out, E);
}